// Round 1
// baseline (189.264 us; speedup 1.0000x reference)
//
#include <hip/hip_runtime.h>
#include <math.h>

// Analytic inverse of [[R, t],[0,0,0,1]] where R comes from normalized quat:
// inv = [[R^T, -R^T t],[0,0,0,1]].
struct Inv {
    float i00, i01, i02, it0;
    float i10, i11, i12, it1;
    float i20, i21, i22, it2;
};

__device__ __forceinline__ Inv make_inv(const float* __restrict__ q,
                                        const float* __restrict__ t, int b) {
    float w = q[b * 4 + 0], x = q[b * 4 + 1], y = q[b * 4 + 2], z = q[b * 4 + 3];
    float inv_n = 1.0f / sqrtf(w * w + x * x + y * y + z * z);
    w *= inv_n; x *= inv_n; y *= inv_n; z *= inv_n;
    // Reference quaternion->R convention (w,x,y,z):
    float R00 = 1.f - 2.f * y * y - 2.f * z * z;
    float R01 = 2.f * x * y - 2.f * z * w;
    float R02 = 2.f * x * z + 2.f * y * w;
    float R10 = 2.f * x * y + 2.f * z * w;
    float R11 = 1.f - 2.f * x * x - 2.f * z * z;
    float R12 = 2.f * y * z - 2.f * x * w;
    float R20 = 2.f * x * z - 2.f * y * w;
    float R21 = 2.f * y * z + 2.f * x * w;
    float R22 = 1.f - 2.f * x * x - 2.f * y * y;
    float t0 = t[b * 3 + 0], t1 = t[b * 3 + 1], t2 = t[b * 3 + 2];
    Inv v;
    v.i00 = R00; v.i01 = R10; v.i02 = R20; v.it0 = -(R00 * t0 + R10 * t1 + R20 * t2);
    v.i10 = R01; v.i11 = R11; v.i12 = R21; v.it1 = -(R01 * t0 + R11 * t1 + R21 * t2);
    v.i20 = R02; v.i21 = R12; v.i22 = R22; v.it2 = -(R02 * t0 + R12 * t1 + R22 * t2);
    return v;
}

__device__ __forceinline__ void xf(const Inv& M, float px, float py, float pz,
                                   float& ox, float& oy, float& oz) {
    ox = fmaf(M.i00, px, fmaf(M.i01, py, fmaf(M.i02, pz, M.it0)));
    oy = fmaf(M.i10, px, fmaf(M.i11, py, fmaf(M.i12, pz, M.it1)));
    oz = fmaf(M.i20, px, fmaf(M.i21, py, fmaf(M.i22, pz, M.it2)));
}

// batch_T_pred[b] = inv_T[b] @ T_mis[b]; one thread per output element (B*16).
__global__ void tmat_kernel(const float* __restrict__ T_mis,
                            const float* __restrict__ q,
                            const float* __restrict__ t,
                            float* __restrict__ out, int total) {
    int tid = blockIdx.x * blockDim.x + threadIdx.x;
    if (tid >= total) return;
    int b = tid >> 4;
    int i = (tid >> 2) & 3;
    int j = tid & 3;
    const float* Tb = T_mis + b * 16;
    float val;
    if (i < 3) {
        Inv M = make_inv(q, t, b);
        float a0, a1, a2, it;
        if (i == 0)      { a0 = M.i00; a1 = M.i01; a2 = M.i02; it = M.it0; }
        else if (i == 1) { a0 = M.i10; a1 = M.i11; a2 = M.i12; it = M.it1; }
        else             { a0 = M.i20; a1 = M.i21; a2 = M.i22; it = M.it2; }
        val = fmaf(a0, Tb[0 * 4 + j],
              fmaf(a1, Tb[1 * 4 + j],
              fmaf(a2, Tb[2 * 4 + j],
                   it * Tb[3 * 4 + j])));
    } else {
        val = Tb[3 * 4 + j];
    }
    out[tid] = val;
}

// pcd_new[b,n,:] = R^T p - R^T t. Each thread: 3x float4 = 12 floats = 4 points.
__global__ __launch_bounds__(256) void pcd_kernel(const float4* __restrict__ pcd,
                                                  const float* __restrict__ q,
                                                  const float* __restrict__ t,
                                                  float4* __restrict__ out,
                                                  int f4_per_batch) {
    const int b = blockIdx.y;          // wave-uniform -> rotation math scalarizes
    Inv M = make_inv(q, t, b);
    const size_t g = (size_t)blockIdx.x * blockDim.x + threadIdx.x;
    const size_t base = (size_t)b * (size_t)f4_per_batch + g * 3u;
    float4 v0 = pcd[base + 0];
    float4 v1 = pcd[base + 1];
    float4 v2 = pcd[base + 2];
    float4 o0, o1, o2;
    xf(M, v0.x, v0.y, v0.z, o0.x, o0.y, o0.z);
    xf(M, v0.w, v1.x, v1.y, o0.w, o1.x, o1.y);
    xf(M, v1.z, v1.w, v2.x, o1.z, o1.w, o2.x);
    xf(M, v2.y, v2.z, v2.w, o2.y, o2.z, o2.w);
    out[base + 0] = o0;
    out[base + 1] = o1;
    out[base + 2] = o2;
}

extern "C" void kernel_launch(void* const* d_in, const int* in_sizes, int n_in,
                              void* d_out, int out_size, void* d_ws, size_t ws_size,
                              hipStream_t stream) {
    const float* pcd   = (const float*)d_in[0];  // (B, N, 3)
    const float* T_mis = (const float*)d_in[1];  // (B, 4, 4)
    const float* q     = (const float*)d_in[2];  // (B, 4)
    const float* t     = (const float*)d_in[3];  // (B, 3)
    float* out = (float*)d_out;

    const int B = in_sizes[2] / 4;              // 32
    const long long N = (long long)in_sizes[0] / (3LL * B);  // 262144

    // Output 0: batch_T_pred, B*16 floats
    {
        int total = B * 16;
        int threads = 256;
        int blocks = (total + threads - 1) / threads;
        tmat_kernel<<<blocks, threads, 0, stream>>>(T_mis, q, t, out, total);
    }

    // Output 1: pcd_new, B*N*3 floats, starting at out+B*16 (float4-aligned: 32*16*4=2048 B)
    {
        const int f4_per_batch = (int)(3 * N / 4);     // 196608
        const int groups_per_batch = (int)(N / 4);     // 65536 (each group = 12 floats)
        const int threads = 256;
        dim3 grid(groups_per_batch / threads, B);      // 256 x 32
        pcd_kernel<<<grid, threads, 0, stream>>>((const float4*)pcd, q, t,
                                                 (float4*)(out + B * 16), f4_per_batch);
    }
}

// Round 2
// 180.215 us; speedup vs baseline: 1.0502x; 1.0502x over previous
//
#include <hip/hip_runtime.h>
#include <math.h>

// Analytic inverse of [[R, t],[0,0,0,1]] where R comes from a normalized quat:
// inv = [[R^T, -R^T t],[0,0,0,1]].
struct Inv {
    float i00, i01, i02, it0;
    float i10, i11, i12, it1;
    float i20, i21, i22, it2;
};

__device__ __forceinline__ Inv make_inv(const float* __restrict__ q,
                                        const float* __restrict__ t, int b) {
    float w = q[b * 4 + 0], x = q[b * 4 + 1], y = q[b * 4 + 2], z = q[b * 4 + 3];
    float inv_n = 1.0f / sqrtf(w * w + x * x + y * y + z * z);
    w *= inv_n; x *= inv_n; y *= inv_n; z *= inv_n;
    float R00 = 1.f - 2.f * y * y - 2.f * z * z;
    float R01 = 2.f * x * y - 2.f * z * w;
    float R02 = 2.f * x * z + 2.f * y * w;
    float R10 = 2.f * x * y + 2.f * z * w;
    float R11 = 1.f - 2.f * x * x - 2.f * z * z;
    float R12 = 2.f * y * z - 2.f * x * w;
    float R20 = 2.f * x * z - 2.f * y * w;
    float R21 = 2.f * y * z + 2.f * x * w;
    float R22 = 1.f - 2.f * x * x - 2.f * y * y;
    float t0 = t[b * 3 + 0], t1 = t[b * 3 + 1], t2 = t[b * 3 + 2];
    Inv v;
    v.i00 = R00; v.i01 = R10; v.i02 = R20; v.it0 = -(R00 * t0 + R10 * t1 + R20 * t2);
    v.i10 = R01; v.i11 = R11; v.i12 = R21; v.it1 = -(R01 * t0 + R11 * t1 + R21 * t2);
    v.i20 = R02; v.i21 = R12; v.i22 = R22; v.it2 = -(R02 * t0 + R12 * t1 + R22 * t2);
    return v;
}

__device__ __forceinline__ void xf(const Inv& M, float px, float py, float pz,
                                   float& ox, float& oy, float& oz) {
    ox = fmaf(M.i00, px, fmaf(M.i01, py, fmaf(M.i02, pz, M.it0)));
    oy = fmaf(M.i10, px, fmaf(M.i11, py, fmaf(M.i12, pz, M.it1)));
    oz = fmaf(M.i20, px, fmaf(M.i21, py, fmaf(M.i22, pz, M.it2)));
}

// One fused kernel:
//  - every block stages a contiguous 768-float4 chunk through LDS so ALL
//    global loads/stores are lane-contiguous float4 (perfect coalescing);
//  - block (0, b), threads 0..15 additionally emit batch_T_pred[b].
// LDS compute-phase pattern: word-stride 12 between lanes -> 8 consecutive
// lanes cover all 32 banks exactly once per ds_read_b128 -> conflict-free.
__global__ __launch_bounds__(256) void realign_fused_kernel(
        const float4* __restrict__ pcd,
        const float* __restrict__ T_mis,
        const float* __restrict__ q,
        const float* __restrict__ t,
        float* __restrict__ out_mat,
        float4* __restrict__ out_pcd,
        int f4_per_batch) {
    __shared__ float4 smem[768];   // 12 KB
    const int b = blockIdx.y;
    const int tid = threadIdx.x;
    const size_t chunk = (size_t)b * (size_t)f4_per_batch + (size_t)blockIdx.x * 768u;

    // Coalesced global -> registers (3 x 1KB/wave per instruction)
    float4 r0 = pcd[chunk + tid];
    float4 r1 = pcd[chunk + 256 + tid];
    float4 r2 = pcd[chunk + 512 + tid];

    const Inv M = make_inv(q, t, b);   // b is wave-uniform -> scalarizes

    smem[tid]       = r0;
    smem[256 + tid] = r1;
    smem[512 + tid] = r2;

    // Fused tmat: batch_T_pred[b] = inv_T[b] @ T_mis[b]
    if (blockIdx.x == 0 && tid < 16) {
        const int i = tid >> 2;
        const int j = tid & 3;
        const float* Tb = T_mis + b * 16;
        float val;
        if (i < 3) {
            float a0, a1, a2, it;
            if (i == 0)      { a0 = M.i00; a1 = M.i01; a2 = M.i02; it = M.it0; }
            else if (i == 1) { a0 = M.i10; a1 = M.i11; a2 = M.i12; it = M.it1; }
            else             { a0 = M.i20; a1 = M.i21; a2 = M.i22; it = M.it2; }
            val = fmaf(a0, Tb[0 * 4 + j],
                  fmaf(a1, Tb[1 * 4 + j],
                  fmaf(a2, Tb[2 * 4 + j],
                       it * Tb[3 * 4 + j])));
        } else {
            val = Tb[3 * 4 + j];
        }
        out_mat[b * 16 + tid] = val;
    }

    __syncthreads();

    // Each thread transforms 4 points (12 floats) read from LDS.
    float4 v0 = smem[3 * tid + 0];
    float4 v1 = smem[3 * tid + 1];
    float4 v2 = smem[3 * tid + 2];
    float4 o0, o1, o2;
    xf(M, v0.x, v0.y, v0.z, o0.x, o0.y, o0.z);
    xf(M, v0.w, v1.x, v1.y, o0.w, o1.x, o1.y);
    xf(M, v1.z, v1.w, v2.x, o1.z, o1.w, o2.x);
    xf(M, v2.y, v2.z, v2.w, o2.y, o2.z, o2.w);
    // Write back to the exact slots this thread read -> no cross-thread hazard.
    smem[3 * tid + 0] = o0;
    smem[3 * tid + 1] = o1;
    smem[3 * tid + 2] = o2;

    __syncthreads();

    // Coalesced LDS -> global stores.
    out_pcd[chunk + tid]       = smem[tid];
    out_pcd[chunk + 256 + tid] = smem[256 + tid];
    out_pcd[chunk + 512 + tid] = smem[512 + tid];
}

extern "C" void kernel_launch(void* const* d_in, const int* in_sizes, int n_in,
                              void* d_out, int out_size, void* d_ws, size_t ws_size,
                              hipStream_t stream) {
    const float* pcd   = (const float*)d_in[0];  // (B, N, 3)
    const float* T_mis = (const float*)d_in[1];  // (B, 4, 4)
    const float* q     = (const float*)d_in[2];  // (B, 4)
    const float* t     = (const float*)d_in[3];  // (B, 3)
    float* out = (float*)d_out;

    const int B = in_sizes[2] / 4;                            // 32
    const long long N = (long long)in_sizes[0] / (3LL * B);   // 262144
    const int f4_per_batch = (int)(3 * N / 4);                // 196608
    const int blocks_x = f4_per_batch / 768;                  // 256

    // Output layout: [0, B*16) = batch_T_pred; then pcd_new (float4-aligned).
    dim3 grid(blocks_x, B);
    realign_fused_kernel<<<grid, 256, 0, stream>>>(
        (const float4*)pcd, T_mis, q, t,
        out, (float4*)(out + B * 16), f4_per_batch);
}